// Round 1
// baseline (2835.344 us; speedup 1.0000x reference)
//
#include <hip/hip_runtime.h>

#define HW   4096
#define CIN  1088
#define CMID 136
#define NB   2

#define TK  16
#define TMN 64

// ---------------------------------------------------------------------------
// Fused per-row stats for conv output: mu1 (mean), rstd (1/sqrt(var+eps)),
// mu2 (mean of LeakyReLU(instance-normed)). One block per (n, o) row of 4096.
// ---------------------------------------------------------------------------
__global__ __launch_bounds__(256) void stats_kernel(const float* __restrict__ Y,
                                                    float* __restrict__ mu1,
                                                    float* __restrict__ rstd,
                                                    float* __restrict__ mu2) {
  const int row = blockIdx.x;  // n*CMID + o
  const float* y = Y + (long)row * HW;
  const int t = threadIdx.x;
  float v[16];
  float s1 = 0.f, s2 = 0.f;
#pragma unroll
  for (int i = 0; i < 16; ++i) {
    v[i] = y[t + i * 256];
    s1 += v[i];
    s2 += v[i] * v[i];
  }
  __shared__ float r1[256], r2[256];
  r1[t] = s1; r2[t] = s2;
  __syncthreads();
  for (int s = 128; s > 0; s >>= 1) {
    if (t < s) { r1[t] += r1[t + s]; r2[t] += r2[t + s]; }
    __syncthreads();
  }
  const float m   = r1[0] * (1.f / HW);
  const float var = r2[0] * (1.f / HW) - m * m;
  const float rs  = 1.f / sqrtf(var + 1e-5f);
  __syncthreads();
  float s3 = 0.f;
#pragma unroll
  for (int i = 0; i < 16; ++i) {
    float x = (v[i] - m) * rs;
    s3 += (x >= 0.f) ? x : 0.2f * x;
  }
  r1[t] = s3;
  __syncthreads();
  for (int s = 128; s > 0; s >>= 1) {
    if (t < s) r1[t] += r1[t + s];
    __syncthreads();
  }
  if (t == 0) {
    mu1[row]  = m;
    rstd[row] = rs;
    mu2[row]  = r1[0] * (1.f / HW);
  }
}

// ---------------------------------------------------------------------------
// Per-spatial-column: apply norm+lrelu+center, L2-normalize over channels.
// In-place on Y. One thread per (n, l).
// ---------------------------------------------------------------------------
__global__ __launch_bounds__(256) void norm_kernel(float* __restrict__ Y,
                                                   const float* __restrict__ mu1,
                                                   const float* __restrict__ rstd,
                                                   const float* __restrict__ mu2) {
  const int n = blockIdx.y;
  const int l = blockIdx.x * 256 + threadIdx.x;
  float* y = Y + (long)n * CMID * HW;
  const float* m1 = mu1  + n * CMID;
  const float* rs = rstd + n * CMID;
  const float* m2 = mu2  + n * CMID;
  float ss = 0.f;
  for (int o = 0; o < CMID; ++o) {
    float x = (y[(long)o * HW + l] - m1[o]) * rs[o];
    x = (x >= 0.f) ? x : 0.2f * x;
    x -= m2[o];
    ss += x * x;
  }
  const float rn = 1.f / sqrtf(ss);
  for (int o = 0; o < CMID; ++o) {
    float x = (y[(long)o * HW + l] - m1[o]) * rs[o];
    x = (x >= 0.f) ? x : 0.2f * x;
    x -= m2[o];
    y[(long)o * HW + l] = x * rn;
  }
}

// ---------------------------------------------------------------------------
// SGEMM NN: C[m][n] = scale * sum_k A[m][k]*B[k][n] (+ bias[m]).
// A: M x K row-major, B: K x N row-major. Requires K % 16 == 0, N % 64 == 0.
// Block 256 threads, 64x64 tile, 4x4 micro-tile.
// ---------------------------------------------------------------------------
__global__ __launch_bounds__(256) void sgemm_nn(const float* __restrict__ A,
                                                const float* __restrict__ Bm,
                                                float* __restrict__ C,
                                                int M, int N, int K,
                                                long sA, long sB, long sC,
                                                const float* __restrict__ bias,
                                                float scale) {
  A  += (long)blockIdx.z * sA;
  Bm += (long)blockIdx.z * sB;
  C  += (long)blockIdx.z * sC;
  const int m0 = blockIdx.y * TMN, n0 = blockIdx.x * TMN;
  __shared__ float As[TK][TMN + 4];
  __shared__ float Bs[TK][TMN + 4];
  const int tid = threadIdx.x;
  const int tx = tid & 15, ty = tid >> 4;
  const int amm = tid >> 2, akk = (tid & 3) * 4;   // A: 64 rows x 4 k-quads
  const int bkk = tid >> 4, bnn = (tid & 15) * 4;  // B: 16 k x 16 n-quads
  const int am = m0 + amm;
  float acc[4][4] = {};
  for (int k0 = 0; k0 < K; k0 += TK) {
    float4 av = make_float4(0.f, 0.f, 0.f, 0.f);
    if (am < M) av = *(const float4*)(A + (long)am * K + (k0 + akk));
    As[akk + 0][amm] = av.x;
    As[akk + 1][amm] = av.y;
    As[akk + 2][amm] = av.z;
    As[akk + 3][amm] = av.w;
    const float4 bv = *(const float4*)(Bm + (long)(k0 + bkk) * N + (n0 + bnn));
    *(float4*)(&Bs[bkk][bnn]) = bv;
    __syncthreads();
#pragma unroll
    for (int kk = 0; kk < TK; ++kk) {
      const float4 a4 = *(const float4*)(&As[kk][ty * 4]);
      const float4 b4 = *(const float4*)(&Bs[kk][tx * 4]);
      const float a[4] = {a4.x, a4.y, a4.z, a4.w};
      const float b[4] = {b4.x, b4.y, b4.z, b4.w};
#pragma unroll
      for (int i = 0; i < 4; ++i)
#pragma unroll
        for (int j = 0; j < 4; ++j)
          acc[i][j] = fmaf(a[i], b[j], acc[i][j]);
    }
    __syncthreads();
  }
#pragma unroll
  for (int i = 0; i < 4; ++i) {
    const int m = m0 + ty * 4 + i;
    if (m < M) {
      const float bs = bias ? bias[m] : 0.f;
      float4 o;
      o.x = acc[i][0] * scale + bs;
      o.y = acc[i][1] * scale + bs;
      o.z = acc[i][2] * scale + bs;
      o.w = acc[i][3] * scale + bs;
      *(float4*)(C + (long)m * N + (n0 + tx * 4)) = o;
    }
  }
}

// ---------------------------------------------------------------------------
// SGEMM TN: C[m][n] = scale * sum_k A[k][m]*B[k][n].
// A: K x M row-major, B: K x N row-major. M,N % 64 == 0; K arbitrary.
// ---------------------------------------------------------------------------
__global__ __launch_bounds__(256) void sgemm_tn(const float* __restrict__ A,
                                                const float* __restrict__ Bm,
                                                float* __restrict__ C,
                                                int M, int N, int K,
                                                long sA, long sB, long sC,
                                                float scale) {
  A  += (long)blockIdx.z * sA;
  Bm += (long)blockIdx.z * sB;
  C  += (long)blockIdx.z * sC;
  const int m0 = blockIdx.y * TMN, n0 = blockIdx.x * TMN;
  __shared__ float As[TK][TMN + 4];
  __shared__ float Bs[TK][TMN + 4];
  const int tid = threadIdx.x;
  const int tx = tid & 15, ty = tid >> 4;
  const int lkk = tid >> 4, lcc = (tid & 15) * 4;
  float acc[4][4] = {};
  for (int k0 = 0; k0 < K; k0 += TK) {
    const int k = k0 + lkk;
    float4 av = make_float4(0.f, 0.f, 0.f, 0.f);
    float4 bv = make_float4(0.f, 0.f, 0.f, 0.f);
    if (k < K) {
      av = *(const float4*)(A + (long)k * M + (m0 + lcc));
      bv = *(const float4*)(Bm + (long)k * N + (n0 + lcc));
    }
    *(float4*)(&As[lkk][lcc]) = av;
    *(float4*)(&Bs[lkk][lcc]) = bv;
    __syncthreads();
#pragma unroll
    for (int kk = 0; kk < TK; ++kk) {
      const float4 a4 = *(const float4*)(&As[kk][ty * 4]);
      const float4 b4 = *(const float4*)(&Bs[kk][tx * 4]);
      const float a[4] = {a4.x, a4.y, a4.z, a4.w};
      const float b[4] = {b4.x, b4.y, b4.z, b4.w};
#pragma unroll
      for (int i = 0; i < 4; ++i)
#pragma unroll
        for (int j = 0; j < 4; ++j)
          acc[i][j] = fmaf(a[i], b[j], acc[i][j]);
    }
    __syncthreads();
  }
#pragma unroll
  for (int i = 0; i < 4; ++i) {
    const int m = m0 + ty * 4 + i;
    float4 o;
    o.x = acc[i][0] * scale;
    o.y = acc[i][1] * scale;
    o.z = acc[i][2] * scale;
    o.w = acc[i][3] * scale;
    *(float4*)(C + (long)m * N + (n0 + tx * 4)) = o;
  }
}

// ---------------------------------------------------------------------------
// Column softmax stats (online max/sum over rows), slab-partial then combine.
// E is (NB, HW, HW); column k, rows l. Coalesced over k.
// ---------------------------------------------------------------------------
__global__ __launch_bounds__(256) void col_partial(const float* __restrict__ E,
                                                   float* __restrict__ pmax,
                                                   float* __restrict__ psum) {
  const int n = blockIdx.z;
  const int slab = blockIdx.y;
  const int k = blockIdx.x * 256 + threadIdx.x;
  const float* Eb = E + (long)n * HW * HW;
  float m = -1e30f, s = 0.f;
  const int l0 = slab * (HW / 16);
  for (int l = l0; l < l0 + (HW / 16); ++l) {
    const float x = Eb[(long)l * HW + k];
    const float mn = fmaxf(m, x);
    s = s * __expf(m - mn) + __expf(x - mn);
    m = mn;
  }
  pmax[((long)n * 16 + slab) * HW + k] = m;
  psum[((long)n * 16 + slab) * HW + k] = s;
}

__global__ __launch_bounds__(256) void col_combine(const float* __restrict__ pmax,
                                                   const float* __restrict__ psum,
                                                   float* __restrict__ cmax,
                                                   float* __restrict__ crs) {
  const int n = blockIdx.y;
  const int k = blockIdx.x * 256 + threadIdx.x;
  float m = -1e30f, s = 0.f;
  for (int i = 0; i < 16; ++i) {
    const float mi = pmax[((long)n * 16 + i) * HW + k];
    const float si = psum[((long)n * 16 + i) * HW + k];
    const float mn = fmaxf(m, mi);
    s = s * __expf(m - mn) + si * __expf(mi - mn);
    m = mn;
  }
  cmax[(long)n * HW + k] = m;
  crs[(long)n * HW + k]  = 1.f / s;
}

// corr_ba_T[n][k][l] = exp(E[n][l][k] - cmax[k]) * crs[k], via LDS transpose.
__global__ __launch_bounds__(256) void col_softmax_T(const float* __restrict__ E,
                                                     const float* __restrict__ cmax,
                                                     const float* __restrict__ crs,
                                                     float* __restrict__ outp) {
  __shared__ float tile[64][65];
  const int n = blockIdx.z;
  const long base = (long)n * HW * HW;
  const int l0 = blockIdx.y * 64, k0 = blockIdx.x * 64;
  const int c = threadIdx.x & 63, r0 = threadIdx.x >> 6;
  const float cm = cmax[(long)n * HW + k0 + c];
  const float cr = crs[(long)n * HW + k0 + c];
  for (int rr = r0; rr < 64; rr += 4) {
    const float x = E[base + (long)(l0 + rr) * HW + (k0 + c)];
    tile[rr][c] = __expf(x - cm) * cr;
  }
  __syncthreads();
  for (int rr = r0; rr < 64; rr += 4) {
    outp[base + (long)(k0 + rr) * HW + (l0 + c)] = tile[c][rr];
  }
}

// Row softmax in place; one block per row of 4096.
__global__ __launch_bounds__(256) void row_softmax(float* __restrict__ E) {
  float* row = E + ((long)blockIdx.y * HW + blockIdx.x) * HW;
  const int t = threadIdx.x;
  float v[16];
  float m = -1e30f;
#pragma unroll
  for (int i = 0; i < 16; ++i) {
    v[i] = row[t + i * 256];
    m = fmaxf(m, v[i]);
  }
  __shared__ float red[256];
  red[t] = m;
  __syncthreads();
  for (int s = 128; s > 0; s >>= 1) {
    if (t < s) red[t] = fmaxf(red[t], red[t + s]);
    __syncthreads();
  }
  m = red[0];
  __syncthreads();
  float s = 0.f;
#pragma unroll
  for (int i = 0; i < 16; ++i) {
    v[i] = __expf(v[i] - m);
    s += v[i];
  }
  red[t] = s;
  __syncthreads();
  for (int s2 = 128; s2 > 0; s2 >>= 1) {
    if (t < s2) red[t] += red[t + s2];
    __syncthreads();
  }
  const float rs = 1.f / red[0];
#pragma unroll
  for (int i = 0; i < 16; ++i) row[t + i * 256] = v[i] * rs;
}

// ---------------------------------------------------------------------------
extern "C" void kernel_launch(void* const* d_in, const int* in_sizes, int n_in,
                              void* d_out, int out_size, void* d_ws, size_t ws_size,
                              hipStream_t stream) {
  const float* fa    = (const float*)d_in[0];
  const float* fb    = (const float*)d_in[1];
  const float* a_raw = (const float*)d_in[2];
  const float* b_raw = (const float*)d_in[3];
  const float* Wa    = (const float*)d_in[4];
  const float* ba    = (const float*)d_in[5];
  const float* Wb    = (const float*)d_in[6];
  const float* bb    = (const float*)d_in[7];

  float* out = (float*)d_out;
  const long S1 = (long)NB * HW * HW;    // corr size
  const long S2 = (long)NB * CIN * HW;   // warp size
  float* corr_ab = out;                  // also holds E before softmax
  float* corr_ba = out + S1;
  float* a_warp  = out + 2 * S1;
  float* b_warp  = out + 2 * S1 + S2;

  float* ws = (float*)d_ws;
  const long szY = (long)NB * CMID * HW;
  float* Ya   = ws;
  float* Yb   = Ya + szY;
  float* mu1  = Yb + szY;                 // [2][NB*CMID]
  float* rstd = mu1 + 2 * NB * CMID;
  float* mu2  = rstd + 2 * NB * CMID;
  float* cmax = mu2 + 2 * NB * CMID;      // [NB][HW]
  float* crs  = cmax + (long)NB * HW;
  float* pmax = crs + (long)NB * HW;      // [NB][16][HW]
  float* psum = pmax + (long)NB * 16 * HW;

  const long strideX = (long)CIN * HW;
  const long strideY = (long)CMID * HW;
  const long strideE = (long)HW * HW;

  // 1) conv 1x1 as GEMM: Y = W @ X + b
  dim3 gConv(HW / TMN, (CMID + TMN - 1) / TMN, NB);
  sgemm_nn<<<gConv, 256, 0, stream>>>(Wa, fa, Ya, CMID, HW, CIN,
                                      0L, strideX, strideY, ba, 1.f);
  sgemm_nn<<<gConv, 256, 0, stream>>>(Wb, fb, Yb, CMID, HW, CIN,
                                      0L, strideX, strideY, bb, 1.f);

  // 2) per-row stats
  stats_kernel<<<dim3(NB * CMID), 256, 0, stream>>>(Ya, mu1, rstd, mu2);
  stats_kernel<<<dim3(NB * CMID), 256, 0, stream>>>(Yb, mu1 + NB * CMID,
                                                    rstd + NB * CMID,
                                                    mu2 + NB * CMID);

  // 3) normalize features in place
  norm_kernel<<<dim3(HW / 256, NB), 256, 0, stream>>>(Ya, mu1, rstd, mu2);
  norm_kernel<<<dim3(HW / 256, NB), 256, 0, stream>>>(Yb, mu1 + NB * CMID,
                                                      rstd + NB * CMID,
                                                      mu2 + NB * CMID);

  // 4) gram: E[k][l] = 100 * sum_o Yb[o][k] * Ya[o][l] -> corr_ab region
  sgemm_tn<<<dim3(HW / TMN, HW / TMN, NB), 256, 0, stream>>>(
      Yb, Ya, corr_ab, HW, HW, CMID, strideY, strideY, strideE, 100.f);

  // 5) column-softmax stats of E
  col_partial<<<dim3(HW / 256, 16, NB), 256, 0, stream>>>(corr_ab, pmax, psum);
  col_combine<<<dim3(HW / 256, NB), 256, 0, stream>>>(pmax, psum, cmax, crs);

  // 6) corr_ba = transposed column softmax of E
  col_softmax_T<<<dim3(HW / 64, HW / 64, NB), 256, 0, stream>>>(corr_ab, cmax,
                                                                crs, corr_ba);

  // 7) corr_ab = row softmax of E (in place; must come after 5 & 6)
  row_softmax<<<dim3(HW, NB), 256, 0, stream>>>(corr_ab);

  // 8) warp GEMMs: warp = raw @ corr
  dim3 gWarp(HW / TMN, CIN / TMN, NB);
  sgemm_nn<<<gWarp, 256, 0, stream>>>(b_raw, corr_ab, b_warp, CIN, HW, HW,
                                      (long)CIN * HW, strideE, (long)CIN * HW,
                                      (const float*)nullptr, 1.f);
  sgemm_nn<<<gWarp, 256, 0, stream>>>(a_raw, corr_ba, a_warp, CIN, HW, HW,
                                      (long)CIN * HW, strideE, (long)CIN * HW,
                                      (const float*)nullptr, 1.f);
}

// Round 2
// 1078.237 us; speedup vs baseline: 2.6296x; 2.6296x over previous
//
#include <hip/hip_runtime.h>

#define HW   4096
#define CIN  1088
#define CMID 136
#define NB   2
#define KPAD 160   // CMID padded to multiple of 32

#define TK  16
#define TMN 64

typedef __attribute__((ext_vector_type(4))) float f32x4;
typedef __attribute__((ext_vector_type(8))) short bf16x8;

__device__ __forceinline__ unsigned short f2bf(float x) {
  unsigned int u = __float_as_uint(x);
  u += 0x7fffu + ((u >> 16) & 1u);
  return (unsigned short)(u >> 16);
}

__device__ __forceinline__ void gld_lds16(const void* g, void* l) {
  __builtin_amdgcn_global_load_lds(
      (const __attribute__((address_space(1))) void*)g,
      (__attribute__((address_space(3))) void*)l, 16, 0, 0);
}

// ---------------------------------------------------------------------------
// MFMA GEMM, both operands bf16 k-contiguous ("BT" layout):
//   A: M x K rows (lda elems/row), B: N x K rows (ldb elems/row)
//   C[m][n] = scale * sum_k A[m][k]*B[n][k],  C fp32 M x N row-major.
// K % 32 == 0, N % 128 == 0; M arbitrary (rows clamped, stores guarded).
// 128x128 tile, 4 waves, 4x4 16x16x32 MFMAs per wave, global_load_lds(16B).
// ---------------------------------------------------------------------------
__global__ __launch_bounds__(256) void gemm_bt_bf16(
    const unsigned short* __restrict__ A, const unsigned short* __restrict__ B,
    float* __restrict__ C, int M, int N, int K, int lda, int ldb,
    long sA, long sB, long sC, float scale) {
  __shared__ unsigned short As[128 * 32];
  __shared__ unsigned short Bs[128 * 32];
  A += (long)blockIdx.z * sA;
  B += (long)blockIdx.z * sB;
  C += (long)blockIdx.z * sC;
  const int tid = threadIdx.x;
  const int lane = tid & 63;
  const int w = tid >> 6;
  const int m0 = blockIdx.y * 128, n0 = blockIdx.x * 128;
  // staging: wave w loads 32 rows of As and Bs (two 16-row segments each)
  const int sr = lane >> 2;         // row within segment
  const int sc = (lane & 3) * 8;    // k-element offset (16 B)
  const int ar0 = min(m0 + 32 * w + sr, M - 1);
  const int ar1 = min(m0 + 32 * w + 16 + sr, M - 1);
  const int br0 = n0 + 32 * w + sr;
  const unsigned short* ga0 = A + (long)ar0 * lda + sc;
  const unsigned short* ga1 = A + (long)ar1 * lda + sc;
  const unsigned short* gb0 = B + (long)br0 * ldb + sc;
  const unsigned short* gb1 = B + (long)(br0 + 16) * ldb + sc;
  unsigned short* lA0 = &As[(32 * w) * 32];
  unsigned short* lA1 = &As[(32 * w + 16) * 32];
  unsigned short* lB0 = &Bs[(32 * w) * 32];
  unsigned short* lB1 = &Bs[(32 * w + 16) * 32];
  // fragment indices
  const int wm = (w >> 1) * 64, wn = (w & 1) * 64;
  const int fr = lane & 15;
  const int fk = (lane >> 4) * 8;
  f32x4 acc[4][4] = {};
  for (int k0 = 0; k0 < K; k0 += 32) {
    __syncthreads();
    gld_lds16(ga0 + k0, lA0);
    gld_lds16(ga1 + k0, lA1);
    gld_lds16(gb0 + k0, lB0);
    gld_lds16(gb1 + k0, lB1);
    __syncthreads();
    bf16x8 af[4], bfv[4];
#pragma unroll
    for (int i = 0; i < 4; ++i)
      af[i] = *(const bf16x8*)&As[(wm + i * 16 + fr) * 32 + fk];
#pragma unroll
    for (int i = 0; i < 4; ++i)
      bfv[i] = *(const bf16x8*)&Bs[(wn + i * 16 + fr) * 32 + fk];
#pragma unroll
    for (int i = 0; i < 4; ++i)
#pragma unroll
      for (int j = 0; j < 4; ++j)
        acc[i][j] =
            __builtin_amdgcn_mfma_f32_16x16x32_bf16(af[i], bfv[j], acc[i][j], 0, 0, 0);
  }
  // C/D layout: col = lane&15, row = (lane>>4)*4 + reg
  const int cr = (lane >> 4) * 4;
  const int cc = lane & 15;
#pragma unroll
  for (int i = 0; i < 4; ++i) {
#pragma unroll
    for (int r = 0; r < 4; ++r) {
      const int m = m0 + wm + i * 16 + cr + r;
      if (m < M) {
        float* cp = C + (long)m * N + n0 + wn + cc;
#pragma unroll
        for (int j = 0; j < 4; ++j) cp[j * 16] = acc[i][j][r] * scale;
      }
    }
  }
}

// ---------------------------------------------------------------------------
// fp32 -> bf16 elementwise convert (vectorized)
// ---------------------------------------------------------------------------
__global__ __launch_bounds__(256) void cvt_bf16(const float* __restrict__ in,
                                                unsigned short* __restrict__ out,
                                                long n4) {
  const long i = (long)blockIdx.x * 256 + threadIdx.x;
  if (i >= n4) return;
  const float4 v = *(const float4*)(in + i * 4);
  ushort4 o;
  o.x = f2bf(v.x); o.y = f2bf(v.y); o.z = f2bf(v.z); o.w = f2bf(v.w);
  *(ushort4*)(out + i * 4) = o;
}

// ---------------------------------------------------------------------------
// Per-row conv-output stats: mu, rstd, mean-after-lrelu.
// ---------------------------------------------------------------------------
__global__ __launch_bounds__(256) void stats_kernel(const float* __restrict__ Y,
                                                    float* __restrict__ mu1,
                                                    float* __restrict__ rstd,
                                                    float* __restrict__ mu2) {
  const int row = blockIdx.x;
  const float* y = Y + (long)row * HW;
  const int t = threadIdx.x;
  float v[16];
  float s1 = 0.f, s2 = 0.f;
#pragma unroll
  for (int i = 0; i < 16; ++i) {
    v[i] = y[t + i * 256];
    s1 += v[i];
    s2 += v[i] * v[i];
  }
  __shared__ float r1[256], r2[256];
  r1[t] = s1; r2[t] = s2;
  __syncthreads();
  for (int s = 128; s > 0; s >>= 1) {
    if (t < s) { r1[t] += r1[t + s]; r2[t] += r2[t + s]; }
    __syncthreads();
  }
  const float m   = r1[0] * (1.f / HW);
  const float var = r2[0] * (1.f / HW) - m * m;
  const float rs  = 1.f / sqrtf(var + 1e-5f);
  __syncthreads();
  float s3 = 0.f;
#pragma unroll
  for (int i = 0; i < 16; ++i) {
    float x = (v[i] - m) * rs;
    s3 += (x >= 0.f) ? x : 0.2f * x;
  }
  r1[t] = s3;
  __syncthreads();
  for (int s = 128; s > 0; s >>= 1) {
    if (t < s) r1[t] += r1[t + s];
    __syncthreads();
  }
  if (t == 0) {
    mu1[row]  = m;
    rstd[row] = rs;
    mu2[row]  = r1[0] * (1.f / HW);
  }
}

// ---------------------------------------------------------------------------
// Tier A: normalize + write bf16 TRANSPOSED features YT[l][o] (ld = KPAD,
// zero-padded cols CMID..KPAD-1). One thread per (n, l).
// ---------------------------------------------------------------------------
__global__ __launch_bounds__(256) void norm_T(const float* __restrict__ Y,
                                              const float* __restrict__ mu1,
                                              const float* __restrict__ rstd,
                                              const float* __restrict__ mu2,
                                              unsigned short* __restrict__ YT) {
  const int n = blockIdx.y;
  const int l = blockIdx.x * 256 + threadIdx.x;
  const float* y = Y + (long)n * CMID * HW;
  const float* m1 = mu1  + n * CMID;
  const float* rs = rstd + n * CMID;
  const float* m2 = mu2  + n * CMID;
  float ss = 0.f;
  for (int o = 0; o < CMID; ++o) {
    float x = (y[(long)o * HW + l] - m1[o]) * rs[o];
    x = (x >= 0.f) ? x : 0.2f * x;
    x -= m2[o];
    ss += x * x;
  }
  const float rn = 1.f / sqrtf(ss);
  unsigned short* yt = YT + ((long)n * HW + l) * KPAD;
  for (int o = 0; o < CMID; ++o) {
    float x = (y[(long)o * HW + l] - m1[o]) * rs[o];
    x = (x >= 0.f) ? x : 0.2f * x;
    x -= m2[o];
    yt[o] = f2bf(x * rn);
  }
  for (int o = CMID; o < KPAD; ++o) yt[o] = 0;
}

// Tier C: in-place fp32 normalize (round-1)
__global__ __launch_bounds__(256) void norm_kernel(float* __restrict__ Y,
                                                   const float* __restrict__ mu1,
                                                   const float* __restrict__ rstd,
                                                   const float* __restrict__ mu2) {
  const int n = blockIdx.y;
  const int l = blockIdx.x * 256 + threadIdx.x;
  float* y = Y + (long)n * CMID * HW;
  const float* m1 = mu1  + n * CMID;
  const float* rs = rstd + n * CMID;
  const float* m2 = mu2  + n * CMID;
  float ss = 0.f;
  for (int o = 0; o < CMID; ++o) {
    float x = (y[(long)o * HW + l] - m1[o]) * rs[o];
    x = (x >= 0.f) ? x : 0.2f * x;
    x -= m2[o];
    ss += x * x;
  }
  const float rn = 1.f / sqrtf(ss);
  for (int o = 0; o < CMID; ++o) {
    float x = (y[(long)o * HW + l] - m1[o]) * rs[o];
    x = (x >= 0.f) ? x : 0.2f * x;
    x -= m2[o];
    y[(long)o * HW + l] = x * rn;
  }
}

// ---------------------------------------------------------------------------
// fp32 SGEMM (round-1 kernels; conv + tier-C fallback)
// ---------------------------------------------------------------------------
__global__ __launch_bounds__(256) void sgemm_nn(const float* __restrict__ A,
                                                const float* __restrict__ Bm,
                                                float* __restrict__ C,
                                                int M, int N, int K,
                                                long sA, long sB, long sC,
                                                const float* __restrict__ bias,
                                                float scale) {
  A  += (long)blockIdx.z * sA;
  Bm += (long)blockIdx.z * sB;
  C  += (long)blockIdx.z * sC;
  const int m0 = blockIdx.y * TMN, n0 = blockIdx.x * TMN;
  __shared__ float As[TK][TMN + 4];
  __shared__ float Bs[TK][TMN + 4];
  const int tid = threadIdx.x;
  const int tx = tid & 15, ty = tid >> 4;
  const int amm = tid >> 2, akk = (tid & 3) * 4;
  const int bkk = tid >> 4, bnn = (tid & 15) * 4;
  const int am = m0 + amm;
  float acc[4][4] = {};
  for (int k0 = 0; k0 < K; k0 += TK) {
    float4 av = make_float4(0.f, 0.f, 0.f, 0.f);
    if (am < M) av = *(const float4*)(A + (long)am * K + (k0 + akk));
    As[akk + 0][amm] = av.x;
    As[akk + 1][amm] = av.y;
    As[akk + 2][amm] = av.z;
    As[akk + 3][amm] = av.w;
    const float4 bv = *(const float4*)(Bm + (long)(k0 + bkk) * N + (n0 + bnn));
    *(float4*)(&Bs[bkk][bnn]) = bv;
    __syncthreads();
#pragma unroll
    for (int kk = 0; kk < TK; ++kk) {
      const float4 a4 = *(const float4*)(&As[kk][ty * 4]);
      const float4 b4 = *(const float4*)(&Bs[kk][tx * 4]);
      const float a[4] = {a4.x, a4.y, a4.z, a4.w};
      const float b[4] = {b4.x, b4.y, b4.z, b4.w};
#pragma unroll
      for (int i = 0; i < 4; ++i)
#pragma unroll
        for (int j = 0; j < 4; ++j)
          acc[i][j] = fmaf(a[i], b[j], acc[i][j]);
    }
    __syncthreads();
  }
#pragma unroll
  for (int i = 0; i < 4; ++i) {
    const int m = m0 + ty * 4 + i;
    if (m < M) {
      const float bs = bias ? bias[m] : 0.f;
      float4 o;
      o.x = acc[i][0] * scale + bs;
      o.y = acc[i][1] * scale + bs;
      o.z = acc[i][2] * scale + bs;
      o.w = acc[i][3] * scale + bs;
      *(float4*)(C + (long)m * N + (n0 + tx * 4)) = o;
    }
  }
}

__global__ __launch_bounds__(256) void sgemm_tn(const float* __restrict__ A,
                                                const float* __restrict__ Bm,
                                                float* __restrict__ C,
                                                int M, int N, int K,
                                                long sA, long sB, long sC,
                                                float scale) {
  A  += (long)blockIdx.z * sA;
  Bm += (long)blockIdx.z * sB;
  C  += (long)blockIdx.z * sC;
  const int m0 = blockIdx.y * TMN, n0 = blockIdx.x * TMN;
  __shared__ float As[TK][TMN + 4];
  __shared__ float Bs[TK][TMN + 4];
  const int tid = threadIdx.x;
  const int tx = tid & 15, ty = tid >> 4;
  const int lkk = tid >> 4, lcc = (tid & 15) * 4;
  float acc[4][4] = {};
  for (int k0 = 0; k0 < K; k0 += TK) {
    const int k = k0 + lkk;
    float4 av = make_float4(0.f, 0.f, 0.f, 0.f);
    float4 bv = make_float4(0.f, 0.f, 0.f, 0.f);
    if (k < K) {
      av = *(const float4*)(A + (long)k * M + (m0 + lcc));
      bv = *(const float4*)(Bm + (long)k * N + (n0 + lcc));
    }
    *(float4*)(&As[lkk][lcc]) = av;
    *(float4*)(&Bs[lkk][lcc]) = bv;
    __syncthreads();
#pragma unroll
    for (int kk = 0; kk < TK; ++kk) {
      const float4 a4 = *(const float4*)(&As[kk][ty * 4]);
      const float4 b4 = *(const float4*)(&Bs[kk][tx * 4]);
      const float a[4] = {a4.x, a4.y, a4.z, a4.w};
      const float b[4] = {b4.x, b4.y, b4.z, b4.w};
#pragma unroll
      for (int i = 0; i < 4; ++i)
#pragma unroll
        for (int j = 0; j < 4; ++j)
          acc[i][j] = fmaf(a[i], b[j], acc[i][j]);
    }
    __syncthreads();
  }
#pragma unroll
  for (int i = 0; i < 4; ++i) {
    const int m = m0 + ty * 4 + i;
    float4 o;
    o.x = acc[i][0] * scale;
    o.y = acc[i][1] * scale;
    o.z = acc[i][2] * scale;
    o.w = acc[i][3] * scale;
    *(float4*)(C + (long)m * N + (n0 + tx * 4)) = o;
  }
}

// ---------------------------------------------------------------------------
// Softmax stats over E (NB, HW, HW)
// ---------------------------------------------------------------------------
__global__ __launch_bounds__(256) void col_partial(const float* __restrict__ E,
                                                   float* __restrict__ pmax,
                                                   float* __restrict__ psum) {
  const int n = blockIdx.z;
  const int slab = blockIdx.y;
  const int k = blockIdx.x * 256 + threadIdx.x;
  const float* Eb = E + (long)n * HW * HW;
  float m = -1e30f, s = 0.f;
  const int l0 = slab * (HW / 16);
  for (int l = l0; l < l0 + (HW / 16); ++l) {
    const float x = Eb[(long)l * HW + k];
    const float mn = fmaxf(m, x);
    s = s * __expf(m - mn) + __expf(x - mn);
    m = mn;
  }
  pmax[((long)n * 16 + slab) * HW + k] = m;
  psum[((long)n * 16 + slab) * HW + k] = s;
}

__global__ __launch_bounds__(256) void col_combine(const float* __restrict__ pmax,
                                                   const float* __restrict__ psum,
                                                   float* __restrict__ cmax,
                                                   float* __restrict__ crs) {
  const int n = blockIdx.y;
  const int k = blockIdx.x * 256 + threadIdx.x;
  float m = -1e30f, s = 0.f;
  for (int i = 0; i < 16; ++i) {
    const float mi = pmax[((long)n * 16 + i) * HW + k];
    const float si = psum[((long)n * 16 + i) * HW + k];
    const float mn = fmaxf(m, mi);
    s = s * __expf(m - mn) + si * __expf(mi - mn);
    m = mn;
  }
  cmax[(long)n * HW + k] = m;
  crs[(long)n * HW + k]  = 1.f / s;
}

__global__ __launch_bounds__(256) void row_stats(const float* __restrict__ E,
                                                 float* __restrict__ rmax,
                                                 float* __restrict__ rrs) {
  const long row = (long)blockIdx.y * HW + blockIdx.x;
  const float* p = E + row * HW;
  const int t = threadIdx.x;
  float v[16];
  float m = -1e30f;
#pragma unroll
  for (int i = 0; i < 16; ++i) {
    v[i] = p[t + i * 256];
    m = fmaxf(m, v[i]);
  }
  __shared__ float red[256];
  red[t] = m;
  __syncthreads();
  for (int s = 128; s > 0; s >>= 1) {
    if (t < s) red[t] = fmaxf(red[t], red[t + s]);
    __syncthreads();
  }
  m = red[0];
  __syncthreads();
  float s = 0.f;
#pragma unroll
  for (int i = 0; i < 16; ++i) s += __expf(v[i] - m);
  red[t] = s;
  __syncthreads();
  for (int s2 = 128; s2 > 0; s2 >>= 1) {
    if (t < s2) red[t] += red[t + s2];
    __syncthreads();
  }
  if (t == 0) {
    rmax[row] = m;
    rrs[row]  = 1.f / red[0];
  }
}

// ---------------------------------------------------------------------------
// Tier A: one pass over E (row-major): corr_ab fp32 (row softmax, in place)
// + baT bf16 [l][k] = corr_ba^T (elementwise: col-softmax scales).
// ---------------------------------------------------------------------------
__global__ __launch_bounds__(256) void row_apply(const float* __restrict__ E,
                                                 const float* __restrict__ rmax,
                                                 const float* __restrict__ rrs,
                                                 const float* __restrict__ cmax,
                                                 const float* __restrict__ crs,
                                                 float* __restrict__ corr_ab,
                                                 unsigned short* __restrict__ baT) {
  const int n = blockIdx.z;
  const int r = blockIdx.y;
  const int c = (blockIdx.x * 256 + threadIdx.x) * 4;
  const long base = (long)n * HW * HW;
  const float4 v = *(const float4*)(E + base + (long)r * HW + c);
  const float rm = rmax[n * HW + r], rv = rrs[n * HW + r];
  const float4 cm = *(const float4*)(cmax + n * HW + c);
  const float4 cv = *(const float4*)(crs + n * HW + c);
  float4 o1;
  o1.x = __expf(v.x - rm) * rv;
  o1.y = __expf(v.y - rm) * rv;
  o1.z = __expf(v.z - rm) * rv;
  o1.w = __expf(v.w - rm) * rv;
  *(float4*)(corr_ab + base + (long)r * HW + c) = o1;
  ushort4 o2;
  o2.x = f2bf(__expf(v.x - cm.x) * cv.x);
  o2.y = f2bf(__expf(v.y - cm.y) * cv.y);
  o2.z = f2bf(__expf(v.z - cm.z) * cv.z);
  o2.w = f2bf(__expf(v.w - cm.w) * cv.w);
  *(ushort4*)(baT + base + (long)r * HW + c) = o2;
}

// ---------------------------------------------------------------------------
// Tier A: transpose pass over E: corr_ba fp32 [k][l] (col softmax, transposed
// write) + abT bf16 [l][k] = corr_ab^T (row-softmax scales, transposed write).
// ---------------------------------------------------------------------------
__global__ __launch_bounds__(256) void col_T(const float* __restrict__ E,
                                             const float* __restrict__ cmax,
                                             const float* __restrict__ crs,
                                             const float* __restrict__ rmax,
                                             const float* __restrict__ rrs,
                                             float* __restrict__ corr_ba,
                                             unsigned short* __restrict__ abT) {
  __shared__ float tile[64][65];
  const int n = blockIdx.z;
  const long base = (long)n * HW * HW;
  const int r0 = blockIdx.y * 64;  // E row range
  const int c0 = blockIdx.x * 64;  // E col range
  const int c = threadIdx.x & 63, rr0 = threadIdx.x >> 6;
  for (int rr = rr0; rr < 64; rr += 4)
    tile[rr][c] = E[base + (long)(r0 + rr) * HW + (c0 + c)];
  const float rm = rmax[n * HW + r0 + c];
  const float rv = rrs[n * HW + r0 + c];
  __syncthreads();
  for (int rr = rr0; rr < 64; rr += 4) {
    const float v = tile[c][rr];  // E[r0+c][c0+rr]
    const float cm = cmax[n * HW + c0 + rr];
    const float cv = crs[n * HW + c0 + rr];
    corr_ba[base + (long)(c0 + rr) * HW + (r0 + c)] = __expf(v - cm) * cv;
    abT[base + (long)(c0 + rr) * HW + (r0 + c)] = f2bf(__expf(v - rm) * rv);
  }
}

// Tier C (round-1): col softmax with transpose only
__global__ __launch_bounds__(256) void col_softmax_T(const float* __restrict__ E,
                                                     const float* __restrict__ cmax,
                                                     const float* __restrict__ crs,
                                                     float* __restrict__ outp) {
  __shared__ float tile[64][65];
  const int n = blockIdx.z;
  const long base = (long)n * HW * HW;
  const int l0 = blockIdx.y * 64, k0 = blockIdx.x * 64;
  const int c = threadIdx.x & 63, r0 = threadIdx.x >> 6;
  const float cm = cmax[(long)n * HW + k0 + c];
  const float cr = crs[(long)n * HW + k0 + c];
  for (int rr = r0; rr < 64; rr += 4) {
    const float x = E[base + (long)(l0 + rr) * HW + (k0 + c)];
    tile[rr][c] = __expf(x - cm) * cr;
  }
  __syncthreads();
  for (int rr = r0; rr < 64; rr += 4) {
    outp[base + (long)(k0 + rr) * HW + (l0 + c)] = tile[c][rr];
  }
}

// Tier C (round-1): row softmax in place
__global__ __launch_bounds__(256) void row_softmax(float* __restrict__ E) {
  float* row = E + ((long)blockIdx.y * HW + blockIdx.x) * HW;
  const int t = threadIdx.x;
  float v[16];
  float m = -1e30f;
#pragma unroll
  for (int i = 0; i < 16; ++i) {
    v[i] = row[t + i * 256];
    m = fmaxf(m, v[i]);
  }
  __shared__ float red[256];
  red[t] = m;
  __syncthreads();
  for (int s = 128; s > 0; s >>= 1) {
    if (t < s) red[t] = fmaxf(red[t], red[t + s]);
    __syncthreads();
  }
  m = red[0];
  __syncthreads();
  float s = 0.f;
#pragma unroll
  for (int i = 0; i < 16; ++i) {
    v[i] = __expf(v[i] - m);
    s += v[i];
  }
  red[t] = s;
  __syncthreads();
  for (int s2 = 128; s2 > 0; s2 >>= 1) {
    if (t < s2) red[t] += red[t + s2];
    __syncthreads();
  }
  const float rs = 1.f / red[0];
#pragma unroll
  for (int i = 0; i < 16; ++i) row[t + i * 256] = v[i] * rs;
}

// ---------------------------------------------------------------------------
extern "C" void kernel_launch(void* const* d_in, const int* in_sizes, int n_in,
                              void* d_out, int out_size, void* d_ws, size_t ws_size,
                              hipStream_t stream) {
  const float* fa    = (const float*)d_in[0];
  const float* fb    = (const float*)d_in[1];
  const float* a_raw = (const float*)d_in[2];
  const float* b_raw = (const float*)d_in[3];
  const float* Wa    = (const float*)d_in[4];
  const float* ba    = (const float*)d_in[5];
  const float* Wb    = (const float*)d_in[6];
  const float* bb    = (const float*)d_in[7];

  float* out = (float*)d_out;
  const long S1 = (long)NB * HW * HW;
  const long S2 = (long)NB * CIN * HW;
  float* corr_ab = out;            // holds E before softmax apply
  float* corr_ba = out + S1;
  float* a_warp  = out + 2 * S1;
  float* b_warp  = out + 2 * S1 + S2;

  const long strideX = (long)CIN * HW;
  const long strideY = (long)CMID * HW;
  const long strideE = (long)HW * HW;

  // ---- tier-A workspace layout (bytes) ----
  const size_t szYT   = (size_t)NB * HW * KPAD * 2;   // bf16 transposed features
  const size_t szRawH = (size_t)NB * CIN * HW * 2;    // bf16 raw
  const size_t szY    = (size_t)NB * CMID * HW * 4;   // fp32 conv out
  const size_t szStat = (size_t)NB * CMID * 4;
  const size_t szVecF = (size_t)NB * HW * 4;
  const size_t szPart = (size_t)NB * 16 * HW * 4;
  const size_t szCorrH = (size_t)NB * HW * HW * 2;    // bf16 corr^T
  const size_t needA = 2 * szYT + 2 * szRawH + 2 * szY + 6 * szStat +
                       4 * szVecF + 2 * szPart + 2 * szCorrH + 256;

  if (ws_size >= needA) {
    // ================= TIER A: MFMA path =================
    char* p = (char*)d_ws;
    unsigned short* YaT   = (unsigned short*)p; p += szYT;
    unsigned short* YbT   = (unsigned short*)p; p += szYT;
    unsigned short* rawAh = (unsigned short*)p; p += szRawH;
    unsigned short* rawBh = (unsigned short*)p; p += szRawH;
    float* Ya   = (float*)p; p += szY;
    float* Yb   = (float*)p; p += szY;
    float* mu1  = (float*)p; p += 2 * szStat;   // [2 dirs][NB*CMID]
    float* rstd = (float*)p; p += 2 * szStat;
    float* mu2  = (float*)p; p += 2 * szStat;
    float* rmax = (float*)p; p += szVecF;
    float* rrs  = (float*)p; p += szVecF;
    float* cmax = (float*)p; p += szVecF;
    float* crs  = (float*)p; p += szVecF;
    float* pmax = (float*)p; p += szPart;
    float* psum = (float*)p; p += szPart;
    unsigned short* abT = (unsigned short*)p; p += szCorrH;
    unsigned short* baT = (unsigned short*)p; p += szCorrH;

    // 1) conv 1x1 (fp32)
    dim3 gConv(HW / TMN, (CMID + TMN - 1) / TMN, NB);
    sgemm_nn<<<gConv, 256, 0, stream>>>(Wa, fa, Ya, CMID, HW, CIN,
                                        0L, strideX, strideY, ba, 1.f);
    sgemm_nn<<<gConv, 256, 0, stream>>>(Wb, fb, Yb, CMID, HW, CIN,
                                        0L, strideX, strideY, bb, 1.f);

    // raw -> bf16 (overlaps nothing, but cheap)
    const long n4raw = (long)NB * CIN * HW / 4;
    cvt_bf16<<<dim3((n4raw + 255) / 256), 256, 0, stream>>>(a_raw, rawAh, n4raw);
    cvt_bf16<<<dim3((n4raw + 255) / 256), 256, 0, stream>>>(b_raw, rawBh, n4raw);

    // 2) stats
    stats_kernel<<<dim3(NB * CMID), 256, 0, stream>>>(Ya, mu1, rstd, mu2);
    stats_kernel<<<dim3(NB * CMID), 256, 0, stream>>>(Yb, mu1 + NB * CMID,
                                                      rstd + NB * CMID,
                                                      mu2 + NB * CMID);

    // 3) normalize -> bf16 transposed (KPAD-padded)
    norm_T<<<dim3(HW / 256, NB), 256, 0, stream>>>(Ya, mu1, rstd, mu2, YaT);
    norm_T<<<dim3(HW / 256, NB), 256, 0, stream>>>(Yb, mu1 + NB * CMID,
                                                   rstd + NB * CMID,
                                                   mu2 + NB * CMID, YbT);

    // 4) gram (MFMA): E[k][l] = 100 * <fb_k, fa_l>
    gemm_bt_bf16<<<dim3(HW / 128, HW / 128, NB), 256, 0, stream>>>(
        YbT, YaT, corr_ab, HW, HW, KPAD, KPAD, KPAD,
        (long)HW * KPAD, (long)HW * KPAD, strideE, 100.f);

    // 5) stats of E
    col_partial<<<dim3(HW / 256, 16, NB), 256, 0, stream>>>(corr_ab, pmax, psum);
    col_combine<<<dim3(HW / 256, NB), 256, 0, stream>>>(pmax, psum, cmax, crs);
    row_stats<<<dim3(HW, NB), 256, 0, stream>>>(corr_ab, rmax, rrs);

    // 6) transpose pass: corr_ba fp32 + abT bf16 (reads E; must precede 7)
    col_T<<<dim3(HW / 64, HW / 64, NB), 256, 0, stream>>>(corr_ab, cmax, crs,
                                                          rmax, rrs, corr_ba, abT);

    // 7) elementwise pass: corr_ab fp32 (in place) + baT bf16
    row_apply<<<dim3(HW / 1024, HW, NB), 256, 0, stream>>>(corr_ab, rmax, rrs,
                                                           cmax, crs, corr_ab, baT);

    // 8) warp GEMMs (MFMA): warp = raw @ corr  (B^T operands)
    dim3 gWarp(HW / 128, (CIN + 127) / 128, NB);
    gemm_bt_bf16<<<gWarp, 256, 0, stream>>>(
        rawBh, abT, b_warp, CIN, HW, HW, HW, HW,
        (long)CIN * HW, strideE, (long)CIN * HW, 1.f);
    gemm_bt_bf16<<<gWarp, 256, 0, stream>>>(
        rawAh, baT, a_warp, CIN, HW, HW, HW, HW,
        (long)CIN * HW, strideE, (long)CIN * HW, 1.f);
  } else {
    // ================= TIER C: round-1 fp32 path =================
    float* ws = (float*)d_ws;
    const long szYf = (long)NB * CMID * HW;
    float* Ya   = ws;
    float* Yb   = Ya + szYf;
    float* mu1  = Yb + szYf;
    float* rstd = mu1 + 2 * NB * CMID;
    float* mu2  = rstd + 2 * NB * CMID;
    float* cmax = mu2 + 2 * NB * CMID;
    float* crs  = cmax + (long)NB * HW;
    float* pmax = crs + (long)NB * HW;
    float* psum = pmax + (long)NB * 16 * HW;

    dim3 gConv(HW / TMN, (CMID + TMN - 1) / TMN, NB);
    sgemm_nn<<<gConv, 256, 0, stream>>>(Wa, fa, Ya, CMID, HW, CIN,
                                        0L, strideX, strideY, ba, 1.f);
    sgemm_nn<<<gConv, 256, 0, stream>>>(Wb, fb, Yb, CMID, HW, CIN,
                                        0L, strideX, strideY, bb, 1.f);
    stats_kernel<<<dim3(NB * CMID), 256, 0, stream>>>(Ya, mu1, rstd, mu2);
    stats_kernel<<<dim3(NB * CMID), 256, 0, stream>>>(Yb, mu1 + NB * CMID,
                                                      rstd + NB * CMID,
                                                      mu2 + NB * CMID);
    norm_kernel<<<dim3(HW / 256, NB), 256, 0, stream>>>(Ya, mu1, rstd, mu2);
    norm_kernel<<<dim3(HW / 256, NB), 256, 0, stream>>>(Yb, mu1 + NB * CMID,
                                                        rstd + NB * CMID,
                                                        mu2 + NB * CMID);
    sgemm_tn<<<dim3(HW / TMN, HW / TMN, NB), 256, 0, stream>>>(
        Yb, Ya, corr_ab, HW, HW, CMID, strideY, strideY, strideE, 100.f);
    col_partial<<<dim3(HW / 256, 16, NB), 256, 0, stream>>>(corr_ab, pmax, psum);
    col_combine<<<dim3(HW / 256, NB), 256, 0, stream>>>(pmax, psum, cmax, crs);
    col_softmax_T<<<dim3(HW / 64, HW / 64, NB), 256, 0, stream>>>(corr_ab, cmax,
                                                                  crs, corr_ba);
    row_softmax<<<dim3(HW, NB), 256, 0, stream>>>(corr_ab);
    dim3 gWarp(HW / TMN, CIN / TMN, NB);
    sgemm_nn<<<gWarp, 256, 0, stream>>>(b_raw, corr_ab, b_warp, CIN, HW, HW,
                                        (long)CIN * HW, strideE, (long)CIN * HW,
                                        (const float*)nullptr, 1.f);
    sgemm_nn<<<gWarp, 256, 0, stream>>>(a_raw, corr_ba, a_warp, CIN, HW, HW,
                                        (long)CIN * HW, strideE, (long)CIN * HW,
                                        (const float*)nullptr, 1.f);
  }
}